// Round 1
// baseline (364.326 us; speedup 1.0000x reference)
//
#include <hip/hip_runtime.h>
#include <math.h>

// [B=2, 1, D=192, H=192, W=192] fp32
#define W 192
#define H 192
#define DEPTH 192
#define BATCH 2
#define TW 64          // tile width
#define TH 8           // tile height
#define DC 16          // output planes per block -> grid 72*12*2 = 1728 blocks (<=2048: all resident)
#define HW (H * W)
#define VOL ((size_t)DEPTH * HW)
#define LROW 72        // LDS row stride (floats), = aligned halo row [w0-4, w0+68)
#define LPLANE (LROW * 10)
#define LBUF (2 * 2 * LPLANE)         // 2880 floats per pair-buffer (pred+gt, 2 planes)
#define NPAIR ((DC + 2) / 2)          // 9 pairs of planes: d0-1 .. d0+16
#define NITEM 720                     // float4 staging items per pair: 2 arrays * 2 planes * 10 rows * 18
#define GX ((W / TW) * (H / TH))      // 72
#define GY (DEPTH / DC)               // 12
#define NBLK (GX * GY * BATCH)        // 1728
#define COUNTER_OFF 7168              // byte offset of arrival counter in workspace (partials: 1728*4=6912B)

__global__ __launch_bounds__(256, 7) void sobel_loss_fused(
    const float* __restrict__ pred, const float* __restrict__ gt,
    const float* __restrict__ mask, float* __restrict__ partials,
    unsigned int* __restrict__ counter, float* __restrict__ out)
{
    // Double-buffered pair staging: exactly 23040 B (256B granule) -> 7 blocks/CU by LDS.
    // Reduction scratch is aliased into the dead buffers after the main loop.
    __shared__ __align__(16) float lds[2][LBUF];

    const int tid = threadIdx.x;
    const int tx = blockIdx.x % 3;          // W tile (0..2)
    const int ty = blockIdx.x / 3;          // H tile (0..23)
    const int w0 = tx * TW, h0 = ty * TH;
    const int d0 = blockIdx.y * DC;
    const size_t base = (size_t)blockIdx.z * VOL;

    // compute-thread geometry: 2 horizontally-adjacent outputs per thread
    const int wy  = tid >> 5;               // row 0..7
    const int wxo = (tid & 31) << 1;        // col 0,2,..,62
    const size_t moff = base + (size_t)(h0 + wy) * W + (w0 + wxo);  // + od*HW

    // ---- staging geometry (3 float4 items/thread, loop-invariant) ----
    // j = tid + 256k < 720: a=j/360 (0=pred,1=gt), q=plane in pair, r=row 0..9, c=col4 0..17
    int it_ok[3], it_st[3], it_q[3], it_lds[3];
    size_t it_goff[3];
    const float* it_src[3];
    #pragma unroll
    for (int k = 0; k < 3; ++k) {
        int j = tid + 256 * k;
        int jj = (j < NITEM) ? j : 0;
        int a = jj / 360; int pj = jj - a * 360;
        int q = pj / 180; int e = pj - q * 180;
        int r = e / 18;   int c = e - r * 18;
        int y  = h0 - 1 + r;
        int xf = w0 - 4 + 4 * c;            // 16B aligned; OOB float4s are fully OOB
        it_st[k]  = (j < NITEM);
        it_ok[k]  = it_st[k] && ((unsigned)y < (unsigned)H) && ((unsigned)xf < (unsigned)W);
        it_goff[k] = it_ok[k] ? ((size_t)y * W + xf) : 0;
        it_lds[k]  = ((a * 2 + q) * 10 + r) * LROW + 4 * c;
        it_q[k]    = q;
        it_src[k]  = a ? gt : pred;
    }

    float4 R[3];
    auto load_pair = [&](int s) {
        const int p0 = d0 - 1 + 2 * s;
        #pragma unroll
        for (int k = 0; k < 3; ++k) {
            const int p = p0 + it_q[k];
            const bool v = it_ok[k] && (p >= 0) && (p < DEPTH);
            R[k] = v ? *(const float4*)(it_src[k] + base + (size_t)p * HW + it_goff[k])
                     : make_float4(0.f, 0.f, 0.f, 0.f);
        }
    };

    float2 Mn = make_float2(0.f, 0.f), Mn1 = make_float2(0.f, 0.f);
    float2 Mc, Mc1;
    auto load_mask = [&](int s) {   // masks for round s outputs: planes d0+2s-2, d0+2s-1
        Mn  = *(const float2*)(mask + moff + (size_t)(d0 + 2 * s - 2) * HW);
        Mn1 = *(const float2*)(mask + moff + (size_t)(d0 + 2 * s - 1) * HW);
    };

    // rolling state: [array][output][age]; ct post-shift: [1]=c(p), [0]=c(p-1)
    float dx[2][2][3], dy[2][2][3], sm[2][2][3], ct[2][2][2];
    #pragma unroll
    for (int a = 0; a < 2; ++a)
        #pragma unroll
        for (int o = 0; o < 2; ++o) {
            dx[a][o][0]=dx[a][o][1]=dx[a][o][2]=0.f;
            dy[a][o][0]=dy[a][o][1]=dy[a][o][2]=0.f;
            sm[a][o][0]=sm[a][o][1]=sm[a][o][2]=0.f;
            ct[a][o][0]=ct[a][o][1]=0.f;
        }
    float acc = 0.f;

    load_pair(0);   // prefetch pair 0

    // One barrier per pair: write pair s into buf[s&1]; barrier; compute from buf[s&1]
    // while issuing loads for pair s+1. Writes of pair s+1 target the other buffer, so
    // no second (read-drain) barrier is needed; skew is bounded by the single barrier.
    for (int s = 0; s < NPAIR; ++s) {
        float* buf = lds[s & 1];
        #pragma unroll
        for (int k = 0; k < 3; ++k)
            if (it_st[k]) *(float4*)(buf + it_lds[k]) = R[k];
        __syncthreads();

        Mc = Mn; Mc1 = Mn1;
        if (s + 1 < NPAIR) {
            load_pair(s + 1);               // issue next pair's loads (no wait)
            load_mask(s + 1);               // masks for round s+1 outputs
        }

        #pragma unroll
        for (int q = 0; q < 2; ++q) {
            const int p = d0 - 1 + 2 * s + q;
            float e[2][3][4];
            #pragma unroll
            for (int a = 0; a < 2; ++a)
                #pragma unroll
                for (int r = 0; r < 3; ++r)
                    #pragma unroll
                    for (int c = 0; c < 4; ++c)
                        e[a][r][c] = buf[(a * 2 + q) * LPLANE + (wy + r) * LROW + wxo + 3 + c];

            #pragma unroll
            for (int a = 0; a < 2; ++a)
                #pragma unroll
                for (int o = 0; o < 2; ++o) {
                    float s0 = e[a][0][o] + 2.f * e[a][0][o+1] + e[a][0][o+2];
                    float s1 = e[a][1][o] + 2.f * e[a][1][o+1] + e[a][1][o+2];
                    float s2 = e[a][2][o] + 2.f * e[a][2][o+1] + e[a][2][o+2];
                    float dd0 = e[a][0][o+2] - e[a][0][o];
                    float dd1 = e[a][1][o+2] - e[a][1][o];
                    float dd2 = e[a][2][o+2] - e[a][2][o];
                    dx[a][o][0] = dx[a][o][1]; dx[a][o][1] = dx[a][o][2]; dx[a][o][2] = dd0 + 2.f * dd1 + dd2;
                    sm[a][o][0] = sm[a][o][1]; sm[a][o][1] = sm[a][o][2]; sm[a][o][2] = s0 + 2.f * s1 + s2;
                    dy[a][o][0] = dy[a][o][1]; dy[a][o][1] = dy[a][o][2]; dy[a][o][2] = s0 - s2;
                    ct[a][o][0] = ct[a][o][1]; ct[a][o][1] = e[a][1][o+1];
                }

            if (p >= d0 + 1) {              // output plane od = p-1; ct[..][0] = c(p-1)
                const float2 M = q ? Mc1 : Mc;
                #pragma unroll
                for (int o = 0; o < 2; ++o) {
                    float gxa = dx[0][o][0] + 2.f * dx[0][o][1] + dx[0][o][2];
                    float gya = dy[0][o][0] + 2.f * dy[0][o][1] + dy[0][o][2];
                    float gza = sm[0][o][0] - sm[0][o][2];
                    float gxb = dx[1][o][0] + 2.f * dx[1][o][1] + dx[1][o][2];
                    float gyb = dy[1][o][0] + 2.f * dy[1][o][1] + dy[1][o][2];
                    float gzb = sm[1][o][0] - sm[1][o][2];
                    float ga = __builtin_amdgcn_sqrtf(gxa * gxa + gya * gya + gza * gza + 1e-10f);
                    float gb = __builtin_amdgcn_sqrtf(gxb * gxb + gyb * gyb + gzb * gzb + 1e-10f);
                    float m  = o ? M.y : M.x;
                    float dm = ct[0][o][0] - ct[1][o][0];
                    float mse = dm * dm * m;
                    float dg  = gb - ga;
                    float mge = dg * dg * m;
                    // tanh(x) = 1 - 2/(e^{2x}+1), x >= 0; saturates via inf -> rcp -> 0
                    float ex = __expf(2.f * mge);
                    float t  = 1.f - 2.f * __builtin_amdgcn_rcpf(ex + 1.f);
                    acc += mse * (1.f + t);
                }
            }
        }
    }

    // ---- block partial reduction (scratch aliased into dead LDS) ----
    float v = acc;
    #pragma unroll
    for (int o = 32; o > 0; o >>= 1) v += __shfl_down(v, o, 64);
    // last compute read lds[ (NPAIR-1)&1 ] = lds[0]; scratch in lds[1] is race-free pre-barrier
    float* redf = &lds[1][0];
    if ((tid & 63) == 0) redf[tid >> 6] = v;
    __syncthreads();

    unsigned int* lastp = (unsigned int*)&lds[0][0];
    if (tid == 0) {
        float bs = redf[0] + redf[1] + redf[2] + redf[3];
        int idx = blockIdx.z * (GX * GY) + blockIdx.y * GX + blockIdx.x;
        partials[idx] = bs;
        __threadfence();                                  // release partials (agent scope)
        unsigned int old = atomicAdd(counter, 1u);        // device-scope arrival
        *lastp = (old == (unsigned int)(NBLK - 1)) ? 1u : 0u;
    }
    __syncthreads();

    if (*lastp) {
        __threadfence();                                  // acquire before re-reading partials
        double sd = 0.0;
        for (int i = tid; i < NBLK; i += 256)
            sd += (double)__hip_atomic_load(&partials[i], __ATOMIC_RELAXED,
                                            __HIP_MEMORY_SCOPE_AGENT);
        #pragma unroll
        for (int o = 32; o > 0; o >>= 1) sd += __shfl_down(sd, o, 64);
        double* dred = (double*)&lds[0][2];               // 8B-aligned, disjoint from lastp
        if ((tid & 63) == 0) dred[tid >> 6] = sd;
        __syncthreads();
        if (tid == 0) {
            double t = dred[0] + dred[1] + dred[2] + dred[3];
            const double ntot = (double)BATCH * (double)DEPTH * (double)H * (double)W;
            out[0] = (float)(t / ntot);
        }
    }
}

extern "C" void kernel_launch(void* const* d_in, const int* in_sizes, int n_in,
                              void* d_out, int out_size, void* d_ws, size_t ws_size,
                              hipStream_t stream) {
    const float* pred = (const float*)d_in[0];
    const float* gt   = (const float*)d_in[1];
    const float* mask = (const float*)d_in[2];
    float* partials = (float*)d_ws;
    unsigned int* counter = (unsigned int*)((char*)d_ws + COUNTER_OFF);

    hipMemsetAsync(counter, 0, sizeof(unsigned int), stream);   // capturable

    dim3 grid(GX, GY, BATCH);   // 72 x 12 x 2 = 1728
    sobel_loss_fused<<<grid, 256, 0, stream>>>(pred, gt, mask, partials, counter, (float*)d_out);
}

// Round 3
// 265.588 us; speedup vs baseline: 1.3718x; 1.3718x over previous
//
#include <hip/hip_runtime.h>
#include <math.h>

// [B=2, 1, D=192, H=192, W=192] fp32
#define W 192
#define H 192
#define DEPTH 192
#define BATCH 2
#define TW 64          // tile width
#define TH 8           // tile height
#define DC 16          // output planes per block -> grid 72*12*2 = 1728 blocks (<=2048: all resident)
#define HW (H * W)
#define VOL ((size_t)DEPTH * HW)
#define LROW 72        // LDS row stride (floats), = aligned halo row [w0-4, w0+68)
#define LPLANE (LROW * 10)
#define LBUF (2 * 2 * LPLANE)         // 2880 floats per pair-buffer (pred+gt, 2 planes)
#define NPAIR ((DC + 2) / 2)          // 9 pairs of planes: d0-1 .. d0+16
#define NITEM 720                     // float4 staging items per pair: 2 arrays * 2 planes * 10 rows * 18
#define GX ((W / TW) * (H / TH))      // 72
#define GY (DEPTH / DC)               // 12
#define NBLK (GX * GY * BATCH)        // 1728
#define COUNTER_OFF 7168              // byte offset of arrival counter in workspace (partials: 1728*4=6912B)

// NOTE: no min-waves arg! __launch_bounds__(256,7) forced VGPR 60->36 and spilled
// the rolling stencil state to scratch (WRITE_SIZE 77KB -> 243MB, dur 71->253us).
// LDS (23040B -> 7 blocks/CU) is the intended occupancy governor; at ~64 VGPR the
// register file is not the limiter, so a register cap buys nothing.
__global__ __launch_bounds__(256) void sobel_loss_fused(
    const float* __restrict__ pred, const float* __restrict__ gt,
    const float* __restrict__ mask, float* __restrict__ partials,
    unsigned int* __restrict__ counter, float* __restrict__ out)
{
    // Double-buffered pair staging: exactly 23040 B (256B granule) -> 7 blocks/CU by LDS.
    // Reduction scratch is aliased into the dead buffers after the main loop.
    __shared__ __align__(16) float lds[2][LBUF];

    const int tid = threadIdx.x;
    const int tx = blockIdx.x % 3;          // W tile (0..2)
    const int ty = blockIdx.x / 3;          // H tile (0..23)
    const int w0 = tx * TW, h0 = ty * TH;
    const int d0 = blockIdx.y * DC;
    const size_t base = (size_t)blockIdx.z * VOL;

    // compute-thread geometry: 2 horizontally-adjacent outputs per thread
    const int wy  = tid >> 5;               // row 0..7
    const int wxo = (tid & 31) << 1;        // col 0,2,..,62
    const size_t moff = base + (size_t)(h0 + wy) * W + (w0 + wxo);  // + od*HW

    // ---- staging geometry (3 float4 items/thread, loop-invariant) ----
    // j = tid + 256k < 720: a=j/360 (0=pred,1=gt), q=plane in pair, r=row 0..9, c=col4 0..17
    int it_ok[3], it_st[3], it_q[3], it_lds[3];
    size_t it_goff[3];
    const float* it_src[3];
    #pragma unroll
    for (int k = 0; k < 3; ++k) {
        int j = tid + 256 * k;
        int jj = (j < NITEM) ? j : 0;
        int a = jj / 360; int pj = jj - a * 360;
        int q = pj / 180; int e = pj - q * 180;
        int r = e / 18;   int c = e - r * 18;
        int y  = h0 - 1 + r;
        int xf = w0 - 4 + 4 * c;            // 16B aligned; OOB float4s are fully OOB
        it_st[k]  = (j < NITEM);
        it_ok[k]  = it_st[k] && ((unsigned)y < (unsigned)H) && ((unsigned)xf < (unsigned)W);
        it_goff[k] = it_ok[k] ? ((size_t)y * W + xf) : 0;
        it_lds[k]  = ((a * 2 + q) * 10 + r) * LROW + 4 * c;
        it_q[k]    = q;
        it_src[k]  = a ? gt : pred;
    }

    float4 R[3];
    auto load_pair = [&](int s) {
        const int p0 = d0 - 1 + 2 * s;
        #pragma unroll
        for (int k = 0; k < 3; ++k) {
            const int p = p0 + it_q[k];
            const bool v = it_ok[k] && (p >= 0) && (p < DEPTH);
            R[k] = v ? *(const float4*)(it_src[k] + base + (size_t)p * HW + it_goff[k])
                     : make_float4(0.f, 0.f, 0.f, 0.f);
        }
    };

    float2 Mn = make_float2(0.f, 0.f), Mn1 = make_float2(0.f, 0.f);
    float2 Mc, Mc1;
    auto load_mask = [&](int s) {   // masks for round s outputs: planes d0+2s-2, d0+2s-1
        Mn  = *(const float2*)(mask + moff + (size_t)(d0 + 2 * s - 2) * HW);
        Mn1 = *(const float2*)(mask + moff + (size_t)(d0 + 2 * s - 1) * HW);
    };

    // rolling state: [array][output][age]; ct post-shift: [1]=c(p), [0]=c(p-1)
    float dx[2][2][3], dy[2][2][3], sm[2][2][3], ct[2][2][2];
    #pragma unroll
    for (int a = 0; a < 2; ++a)
        #pragma unroll
        for (int o = 0; o < 2; ++o) {
            dx[a][o][0]=dx[a][o][1]=dx[a][o][2]=0.f;
            dy[a][o][0]=dy[a][o][1]=dy[a][o][2]=0.f;
            sm[a][o][0]=sm[a][o][1]=sm[a][o][2]=0.f;
            ct[a][o][0]=ct[a][o][1]=0.f;
        }
    float acc = 0.f;

    load_pair(0);   // prefetch pair 0

    // One barrier per pair: write pair s into buf[s&1]; barrier; compute from buf[s&1]
    // while issuing loads for pair s+1. Writes of pair s+1 target the other buffer, so
    // no second (read-drain) barrier is needed; skew is bounded by the single barrier:
    // reads of buf[s&1] finish before the s+1 barrier; the next write to that buffer
    // happens after it (iteration s+2).
    for (int s = 0; s < NPAIR; ++s) {
        float* buf = lds[s & 1];
        #pragma unroll
        for (int k = 0; k < 3; ++k)
            if (it_st[k]) *(float4*)(buf + it_lds[k]) = R[k];
        __syncthreads();

        Mc = Mn; Mc1 = Mn1;
        if (s + 1 < NPAIR) {
            load_pair(s + 1);               // issue next pair's loads (no wait)
            load_mask(s + 1);               // masks for round s+1 outputs
        }

        #pragma unroll
        for (int q = 0; q < 2; ++q) {
            const int p = d0 - 1 + 2 * s + q;
            float e[2][3][4];
            #pragma unroll
            for (int a = 0; a < 2; ++a)
                #pragma unroll
                for (int r = 0; r < 3; ++r)
                    #pragma unroll
                    for (int c = 0; c < 4; ++c)
                        e[a][r][c] = buf[(a * 2 + q) * LPLANE + (wy + r) * LROW + wxo + 3 + c];

            #pragma unroll
            for (int a = 0; a < 2; ++a)
                #pragma unroll
                for (int o = 0; o < 2; ++o) {
                    float s0 = e[a][0][o] + 2.f * e[a][0][o+1] + e[a][0][o+2];
                    float s1 = e[a][1][o] + 2.f * e[a][1][o+1] + e[a][1][o+2];
                    float s2 = e[a][2][o] + 2.f * e[a][2][o+1] + e[a][2][o+2];
                    float dd0 = e[a][0][o+2] - e[a][0][o];
                    float dd1 = e[a][1][o+2] - e[a][1][o];
                    float dd2 = e[a][2][o+2] - e[a][2][o];
                    dx[a][o][0] = dx[a][o][1]; dx[a][o][1] = dx[a][o][2]; dx[a][o][2] = dd0 + 2.f * dd1 + dd2;
                    sm[a][o][0] = sm[a][o][1]; sm[a][o][1] = sm[a][o][2]; sm[a][o][2] = s0 + 2.f * s1 + s2;
                    dy[a][o][0] = dy[a][o][1]; dy[a][o][1] = dy[a][o][2]; dy[a][o][2] = s0 - s2;
                    ct[a][o][0] = ct[a][o][1]; ct[a][o][1] = e[a][1][o+1];
                }

            if (p >= d0 + 1) {              // output plane od = p-1; ct[..][0] = c(p-1)
                const float2 M = q ? Mc1 : Mc;
                #pragma unroll
                for (int o = 0; o < 2; ++o) {
                    float gxa = dx[0][o][0] + 2.f * dx[0][o][1] + dx[0][o][2];
                    float gya = dy[0][o][0] + 2.f * dy[0][o][1] + dy[0][o][2];
                    float gza = sm[0][o][0] - sm[0][o][2];
                    float gxb = dx[1][o][0] + 2.f * dx[1][o][1] + dx[1][o][2];
                    float gyb = dy[1][o][0] + 2.f * dy[1][o][1] + dy[1][o][2];
                    float gzb = sm[1][o][0] - sm[1][o][2];
                    float ga = __builtin_amdgcn_sqrtf(gxa * gxa + gya * gya + gza * gza + 1e-10f);
                    float gb = __builtin_amdgcn_sqrtf(gxb * gxb + gyb * gyb + gzb * gzb + 1e-10f);
                    float m  = o ? M.y : M.x;
                    float dm = ct[0][o][0] - ct[1][o][0];
                    float mse = dm * dm * m;
                    float dg  = gb - ga;
                    float mge = dg * dg * m;
                    // tanh(x) = 1 - 2/(e^{2x}+1), x >= 0; saturates via inf -> rcp -> 0
                    float ex = __expf(2.f * mge);
                    float t  = 1.f - 2.f * __builtin_amdgcn_rcpf(ex + 1.f);
                    acc += mse * (1.f + t);
                }
            }
        }
    }

    // ---- block partial reduction (scratch aliased into dead LDS) ----
    float v = acc;
    #pragma unroll
    for (int o = 32; o > 0; o >>= 1) v += __shfl_down(v, o, 64);
    // last compute read lds[ (NPAIR-1)&1 ] = lds[0]; scratch in lds[1] is race-free pre-barrier
    float* redf = &lds[1][0];
    if ((tid & 63) == 0) redf[tid >> 6] = v;
    __syncthreads();

    unsigned int* lastp = (unsigned int*)&lds[0][0];
    if (tid == 0) {
        float bs = redf[0] + redf[1] + redf[2] + redf[3];
        int idx = blockIdx.z * (GX * GY) + blockIdx.y * GX + blockIdx.x;
        partials[idx] = bs;
        __threadfence();                                  // release partials (agent scope)
        unsigned int old = atomicAdd(counter, 1u);        // device-scope arrival
        *lastp = (old == (unsigned int)(NBLK - 1)) ? 1u : 0u;
    }
    __syncthreads();

    if (*lastp) {
        __threadfence();                                  // acquire before re-reading partials
        double sd = 0.0;
        for (int i = tid; i < NBLK; i += 256)
            sd += (double)__hip_atomic_load(&partials[i], __ATOMIC_RELAXED,
                                            __HIP_MEMORY_SCOPE_AGENT);
        #pragma unroll
        for (int o = 32; o > 0; o >>= 1) sd += __shfl_down(sd, o, 64);
        double* dred = (double*)&lds[0][2];               // 8B-aligned, disjoint from lastp
        if ((tid & 63) == 0) dred[tid >> 6] = sd;
        __syncthreads();
        if (tid == 0) {
            double t = dred[0] + dred[1] + dred[2] + dred[3];
            const double ntot = (double)BATCH * (double)DEPTH * (double)H * (double)W;
            out[0] = (float)(t / ntot);
        }
    }
}

extern "C" void kernel_launch(void* const* d_in, const int* in_sizes, int n_in,
                              void* d_out, int out_size, void* d_ws, size_t ws_size,
                              hipStream_t stream) {
    const float* pred = (const float*)d_in[0];
    const float* gt   = (const float*)d_in[1];
    const float* mask = (const float*)d_in[2];
    float* partials = (float*)d_ws;   // needs COUNTER_OFF+4 = 7172 B of workspace
    unsigned int* counter = (unsigned int*)((char*)d_ws + COUNTER_OFF);

    hipMemsetAsync(counter, 0, sizeof(unsigned int), stream);   // capturable

    dim3 grid(GX, GY, BATCH);   // 72 x 12 x 2 = 1728
    sobel_loss_fused<<<grid, 256, 0, stream>>>(pred, gt, mask, partials, counter, (float*)d_out);
}

// Round 4
// 184.997 us; speedup vs baseline: 1.9694x; 1.4356x over previous
//
#include <hip/hip_runtime.h>
#include <math.h>

// [B=2, 1, D=192, H=192, W=192] fp32
#define W 192
#define H 192
#define DEPTH 192
#define BATCH 2
#define TW 64          // tile width
#define TH 8           // tile height
#define DC 12          // output planes per block -> grid 72*16*2 = 2304 blocks (round-0 proven)
#define HW (H * W)
#define VOL ((size_t)DEPTH * HW)
#define LROW 72        // LDS row stride (floats), = aligned halo row [w0-4, w0+68)
#define LPLANE (LROW * 10)
#define NPAIR ((DC + 2) / 2)      // 7 pairs of planes: d0-1 .. d0+12
#define NITEM 720                 // float4 staging items per pair: 2 arrays * 2 planes * 10 rows * 18

// Round-0 structure (71.7us proven: two barriers, separate reduce kernel, DC=12).
// Single change vs round 0: wave-owns-row-pair compute geometry so every stencil
// LDS read is 64 consecutive floats (2 lanes/bank = free) instead of the old
// even-strided pattern (all lanes on odd banks = 4-way conflict, 5.68M cycles).
__global__ __launch_bounds__(256) void sobel_loss_part(
    const float* __restrict__ pred, const float* __restrict__ gt,
    const float* __restrict__ mask, float* __restrict__ partials)
{
    __shared__ __align__(16) float lds[2 * 2 * LPLANE];   // [array][planeq][10 rows * 72]

    const int tid = threadIdx.x;
    const int tx = blockIdx.x % 3;          // W tile (0..2)
    const int ty = blockIdx.x / 3;          // H tile (0..23)
    const int w0 = tx * TW, h0 = ty * TH;
    const int d0 = blockIdx.y * DC;
    const size_t base = (size_t)blockIdx.z * VOL;

    // compute-thread geometry: wave wv owns rows (2wv, 2wv+1); lane = column
    const int wv  = tid >> 6;               // wave 0..3 -> row pair
    const int col = tid & 63;               // column 0..63
    const size_t moff = base + (size_t)(h0 + 2 * wv) * W + (w0 + col);  // row A; row B = +W

    // ---- staging geometry (3 float4 items/thread, loop-invariant; unchanged) ----
    // j = tid + 256k < 720: a=j/360 (0=pred,1=gt), q=plane in pair, r=row 0..9, c=col4 0..17
    int it_ok[3], it_st[3], it_q[3], it_lds[3];
    size_t it_goff[3];
    const float* it_src[3];
    #pragma unroll
    for (int k = 0; k < 3; ++k) {
        int j = tid + 256 * k;
        int jj = (j < NITEM) ? j : 0;
        int a = jj / 360; int pj = jj - a * 360;
        int q = pj / 180; int e = pj - q * 180;
        int r = e / 18;   int c = e - r * 18;
        int y  = h0 - 1 + r;
        int xf = w0 - 4 + 4 * c;            // 16B aligned; OOB float4s are fully OOB
        it_st[k]  = (j < NITEM);
        it_ok[k]  = it_st[k] && ((unsigned)y < (unsigned)H) && ((unsigned)xf < (unsigned)W);
        it_goff[k] = it_ok[k] ? ((size_t)y * W + xf) : 0;
        it_lds[k]  = ((a * 2 + q) * 10 + r) * LROW + 4 * c;
        it_q[k]    = q;
        it_src[k]  = a ? gt : pred;
    }

    float4 R[3];
    auto load_pair = [&](int s) {
        const int p0 = d0 - 1 + 2 * s;
        #pragma unroll
        for (int k = 0; k < 3; ++k) {
            const int p = p0 + it_q[k];
            const bool v = it_ok[k] && (p >= 0) && (p < DEPTH);
            R[k] = v ? *(const float4*)(it_src[k] + base + (size_t)p * HW + it_goff[k])
                     : make_float4(0.f, 0.f, 0.f, 0.f);
        }
    };

    float2 Mn = make_float2(0.f, 0.f), Mn1 = make_float2(0.f, 0.f);
    float2 Mc, Mc1;
    auto load_mask = [&](int s) {   // masks for round s outputs: planes d0+2s-2, d0+2s-1
        const size_t p0 = moff + (size_t)(d0 + 2 * s - 2) * HW;
        Mn  = make_float2(mask[p0], mask[p0 + W]);            // .x = row A, .y = row B
        Mn1 = make_float2(mask[p0 + HW], mask[p0 + HW + W]);
    };

    // rolling state: [array][row-in-pair][age]; ct post-shift: [1]=c(p), [0]=c(p-1)
    float dx[2][2][3], dy[2][2][3], sm[2][2][3], ct[2][2][2];
    #pragma unroll
    for (int a = 0; a < 2; ++a)
        #pragma unroll
        for (int o = 0; o < 2; ++o) {
            dx[a][o][0]=dx[a][o][1]=dx[a][o][2]=0.f;
            dy[a][o][0]=dy[a][o][1]=dy[a][o][2]=0.f;
            sm[a][o][0]=sm[a][o][1]=sm[a][o][2]=0.f;
            ct[a][o][0]=ct[a][o][1]=0.f;
        }
    float acc = 0.f;

    load_pair(0);   // prefetch pair 0

    for (int s = 0; s < NPAIR; ++s) {
        __syncthreads();                    // previous round's LDS reads complete
        #pragma unroll
        for (int k = 0; k < 3; ++k)
            if (it_st[k]) *(float4*)(lds + it_lds[k]) = R[k];
        __syncthreads();

        Mc = Mn; Mc1 = Mn1;
        if (s + 1 < NPAIR) {
            load_pair(s + 1);               // issue next pair's loads (no wait)
            load_mask(s + 1);               // masks for round s+1 outputs
        }

        #pragma unroll
        for (int q = 0; q < 2; ++q) {
            const int p = d0 - 1 + 2 * s + q;

            #pragma unroll
            for (int a = 0; a < 2; ++a) {
                const int ab = (a * 2 + q) * LPLANE + (2 * wv) * LROW + col + 3;
                float e[4][3];
                #pragma unroll
                for (int rr = 0; rr < 4; ++rr)
                    #pragma unroll
                    for (int d = 0; d < 3; ++d)
                        e[rr][d] = lds[ab + rr * LROW + d];   // 64 consecutive floats/lane-set

                float rs[4], rd[4];
                #pragma unroll
                for (int rr = 0; rr < 4; ++rr) {
                    rs[rr] = e[rr][0] + 2.f * e[rr][1] + e[rr][2];
                    rd[rr] = e[rr][2] - e[rr][0];
                }
                #pragma unroll
                for (int o = 0; o < 2; ++o) {   // o = row within pair
                    dx[a][o][0] = dx[a][o][1]; dx[a][o][1] = dx[a][o][2];
                    dx[a][o][2] = rd[o] + 2.f * rd[o+1] + rd[o+2];
                    sm[a][o][0] = sm[a][o][1]; sm[a][o][1] = sm[a][o][2];
                    sm[a][o][2] = rs[o] + 2.f * rs[o+1] + rs[o+2];
                    dy[a][o][0] = dy[a][o][1]; dy[a][o][1] = dy[a][o][2];
                    dy[a][o][2] = rs[o] - rs[o+2];
                    ct[a][o][0] = ct[a][o][1]; ct[a][o][1] = e[o+1][1];
                }
            }

            if (p >= d0 + 1) {              // output plane od = p-1; ct[..][0] = c(p-1)
                const float2 M = q ? Mc1 : Mc;
                #pragma unroll
                for (int o = 0; o < 2; ++o) {
                    float gxa = dx[0][o][0] + 2.f * dx[0][o][1] + dx[0][o][2];
                    float gya = dy[0][o][0] + 2.f * dy[0][o][1] + dy[0][o][2];
                    float gza = sm[0][o][0] - sm[0][o][2];
                    float gxb = dx[1][o][0] + 2.f * dx[1][o][1] + dx[1][o][2];
                    float gyb = dy[1][o][0] + 2.f * dy[1][o][1] + dy[1][o][2];
                    float gzb = sm[1][o][0] - sm[1][o][2];
                    float ga = __builtin_amdgcn_sqrtf(gxa * gxa + gya * gya + gza * gza + 1e-10f);
                    float gb = __builtin_amdgcn_sqrtf(gxb * gxb + gyb * gyb + gzb * gzb + 1e-10f);
                    float m  = o ? M.y : M.x;
                    float dm = ct[0][o][0] - ct[1][o][0];
                    float mse = dm * dm * m;
                    float dg  = gb - ga;
                    float mge = dg * dg * m;
                    // tanh(x) = 1 - 2/(e^{2x}+1), x >= 0; saturates via inf -> rcp -> 0
                    float ex = __expf(2.f * mge);
                    float t  = 1.f - 2.f * __builtin_amdgcn_rcpf(ex + 1.f);
                    acc += mse * (1.f + t);
                }
            }
        }
    }

    // block reduction
    float v = acc;
    #pragma unroll
    for (int o = 32; o > 0; o >>= 1) v += __shfl_down(v, o, 64);
    __shared__ float red[4];
    if ((tid & 63) == 0) red[tid >> 6] = v;
    __syncthreads();
    if (tid == 0) {
        partials[(size_t)blockIdx.z * (gridDim.x * gridDim.y)
                 + (size_t)blockIdx.y * gridDim.x + blockIdx.x]
            = red[0] + red[1] + red[2] + red[3];
    }
}

__global__ __launch_bounds__(256) void reduce_final(
    const float* __restrict__ partials, int n, float* __restrict__ out)
{
    int tid = threadIdx.x;
    double s = 0.0;
    for (int i = tid; i < n; i += 256) s += (double)partials[i];
    #pragma unroll
    for (int o = 32; o > 0; o >>= 1) s += __shfl_down(s, o, 64);
    __shared__ double red[4];
    if ((tid & 63) == 0) red[tid >> 6] = s;
    __syncthreads();
    if (tid == 0) {
        double t = red[0] + red[1] + red[2] + red[3];
        const double ntot = (double)BATCH * (double)DEPTH * (double)H * (double)W;
        out[0] = (float)(t / ntot);
    }
}

extern "C" void kernel_launch(void* const* d_in, const int* in_sizes, int n_in,
                              void* d_out, int out_size, void* d_ws, size_t ws_size,
                              hipStream_t stream) {
    const float* pred = (const float*)d_in[0];
    const float* gt   = (const float*)d_in[1];
    const float* mask = (const float*)d_in[2];
    float* partials = (float*)d_ws;

    dim3 grid((W / TW) * (H / TH), DEPTH / DC, BATCH);   // 72 x 16 x 2 = 2304
    sobel_loss_part<<<grid, 256, 0, stream>>>(pred, gt, mask, partials);

    int nparts = grid.x * grid.y * grid.z;
    reduce_final<<<1, 256, 0, stream>>>(partials, nparts, (float*)d_out);
}